// Round 7
// baseline (864.174 us; speedup 1.0000x reference)
//
#include <hip/hip_runtime.h>
#include <hip/hip_bf16.h>
#include <math.h>

#define NTOK 4096
#define CDIM 128

typedef __attribute__((ext_vector_type(4))) float f32x4;
typedef __attribute__((ext_vector_type(8))) short bfx8;

__device__ __forceinline__ float geluf(float z){
  return 0.5f*z*(1.0f+erff(z*0.70710678118654752440f));
}
__device__ __forceinline__ float softplusf(float x){
  return (x>20.0f)?x:log1pf(expf(x));
}
__device__ __forceinline__ ushort f2bf(float f){
  __hip_bfloat16 h=__float2bfloat16(f);
  return *reinterpret_cast<ushort*>(&h);
}

// ============ weight conversion to bf16 (+padding): proj, fc1, fc2 only ============
__global__ __launch_bounds__(256) void convw_kernel(
  const float* __restrict__ projw, const float* __restrict__ fc1w,
  const float* __restrict__ fc2w,
  ushort* __restrict__ pwb, ushort* __restrict__ f1wb, ushort* __restrict__ f2wb){
  int id=blockIdx.x*256+threadIdx.x;
  if(id<16384) pwb[id]=f2bf(projw[id]);
  else if(id<106496){ int t=id-16384; int nn=t>>7,k=t&127;
    f1wb[t]=f2bf(nn<682? fc1w[nn*128+k] : 0.0f); }
  else if(id<155648){ int t=id-106496; int nn=t/384,k=t-nn*384;
    f2wb[t]=f2bf(k<341? fc2w[nn*341+k] : 0.0f); }
}

// ============ LayerNorm fp32 out ============
__global__ __launch_bounds__(128) void ln_f32_kernel(const float* __restrict__ in,
    const float* __restrict__ g, const float* __restrict__ bb, float* __restrict__ out){
  int t=blockIdx.x, c=threadIdx.x;
  float v=in[(size_t)t*CDIM+c];
  __shared__ float red[2];
  float s=v;
  #pragma unroll
  for(int m=1;m<64;m<<=1) s+=__shfl_xor(s,m);
  if((c&63)==0) red[c>>6]=s;
  __syncthreads();
  float mean=(red[0]+red[1])*(1.0f/CDIM);
  float d=v-mean;
  __syncthreads();
  float s2=d*d;
  #pragma unroll
  for(int m=1;m<64;m<<=1) s2+=__shfl_xor(s2,m);
  if((c&63)==0) red[c>>6]=s2;
  __syncthreads();
  float var=(red[0]+red[1])*(1.0f/CDIM);
  out[(size_t)t*CDIM+c]=d*rsqrtf(var+1e-5f)*g[c]+bb[c];
}

// ============ LayerNorm bf16 out ============
__global__ __launch_bounds__(128) void ln_bf_kernel(const float* __restrict__ in,
    const float* __restrict__ g, const float* __restrict__ bb, ushort* __restrict__ out){
  int t=blockIdx.x, c=threadIdx.x;
  float v=in[(size_t)t*CDIM+c];
  __shared__ float red[2];
  float s=v;
  #pragma unroll
  for(int m=1;m<64;m<<=1) s+=__shfl_xor(s,m);
  if((c&63)==0) red[c>>6]=s;
  __syncthreads();
  float mean=(red[0]+red[1])*(1.0f/CDIM);
  float d=v-mean;
  __syncthreads();
  float s2=d*d;
  #pragma unroll
  for(int m=1;m<64;m<<=1) s2+=__shfl_xor(s2,m);
  if((c&63)==0) red[c>>6]=s2;
  __syncthreads();
  float var=(red[0]+red[1])*(1.0f/CDIM);
  out[(size_t)t*CDIM+c]=f2bf(d*rsqrtf(var+1e-5f)*g[c]+bb[c]);
}

// ============ q proj + l2 norm + scale (verified, fp32) ============
__global__ __launch_bounds__(128) void qproj_kernel(const float* __restrict__ h,
  const float* __restrict__ qw, const float* __restrict__ qemb,
  const float* __restrict__ temp, const float* __restrict__ seqs,
  float* __restrict__ qsout, float* __restrict__ qnout){
  int t0=blockIdx.x*8;
  int o=threadIdx.x;
  __shared__ float hr[8][128];
  for(int i=o;i<1024;i+=128) hr[i>>7][i&127]=h[(size_t)t0*128+i];
  __syncthreads();
  const float* wr=qw+(size_t)o*128;
  float a[8]={0,0,0,0,0,0,0,0};
  for(int c=0;c<128;c++){
    float wv=wr[c];
    #pragma unroll
    for(int tt=0;tt<8;tt++) a[tt]+=hr[tt][c]*wv;
  }
  int hh=o>>5, d=o&31;
  float emb=qemb[hh*32+d];
  float scale=softplusf(temp[hh])*seqs[0];
  #pragma unroll
  for(int tt=0;tt<8;tt++){
    float ss=a[tt]*a[tt];
    #pragma unroll
    for(int m=1;m<32;m<<=1) ss+=__shfl_xor(ss,m);
    float qnv=a[tt]/fmaxf(sqrtf(ss),1e-12f);
    qnout[(size_t)(t0+tt)*128+o]=qnv;
    qsout[(size_t)(t0+tt)*128+o]=(qnv+emb)*scale;
  }
}

// ============ kv proj (verified math) -> TOKEN-major (B,N,256) ============
__global__ __launch_bounds__(256) void kvproj_kernel(const float* __restrict__ h,
  const float* __restrict__ kvw, float* __restrict__ kv_tm){
  int t0=blockIdx.x*8;
  int tid=threadIdx.x;
  __shared__ float hr[8][128];
  for(int i=tid;i<1024;i+=256) hr[i>>7][i&127]=h[(size_t)t0*128+i];
  __syncthreads();
  const float* wr=kvw+(size_t)tid*128;
  float a[8]={0,0,0,0,0,0,0,0};
  for(int c=0;c<128;c++){
    float wv=wr[c];
    #pragma unroll
    for(int tt=0;tt<8;tt++) a[tt]+=hr[tt][c]*wv;
  }
  #pragma unroll
  for(int tt=0;tt<8;tt++){
    float v=a[tt];
    if(tid<128){
      float ss=v*v;
      #pragma unroll
      for(int m=1;m<32;m<<=1) ss+=__shfl_xor(ss,m);
      v/=fmaxf(sqrtf(ss),1e-12f);
    }
    kv_tm[(size_t)(t0+tt)*256+tid]=v;   // token-major store (pure index permutation)
  }
}

// ============ sr 1x1 conv + gelu + 8x8 avg pool (verified) ============
__global__ __launch_bounds__(128) void srpool_kernel(const float* __restrict__ h,
  const float* __restrict__ srw, const float* __restrict__ srb, float* __restrict__ xipre){
  int bp=blockIdx.x;
  int b=bp>>6, pp=bp&63;
  int py=pp>>3, px=pp&7;
  int o=threadIdx.x;
  __shared__ float hr[64][128];
  for(int i=0;i<64;i++){
    int yy=py*8+(i>>3), xx=px*8+(i&7);
    hr[i][o]=h[((size_t)b*NTOK+yy*64+xx)*128+o];
  }
  __syncthreads();
  const float* wr=srw+(size_t)o*128;
  float bias=srb[o];
  float acc=0;
  for(int i=0;i<64;i++){
    float s=bias;
    for(int c=0;c<128;c++) s+=hr[i][c]*wr[c];
    acc+=geluf(s);
  }
  xipre[(size_t)bp*128+o]=acc*(1.0f/64.0f);
}

// ============ pooled kv proj (verified) ============
__global__ __launch_bounds__(256) void kvp_kernel(const float* __restrict__ xi,
  const float* __restrict__ kvw, float* __restrict__ kpb, float* __restrict__ vpb){
  int bp=blockIdx.x;
  int b=bp>>6, p=bp&63;
  int o=threadIdx.x;
  __shared__ float xr[128];
  if(o<128) xr[o]=xi[(size_t)bp*128+o];
  __syncthreads();
  const float* wr=kvw+(size_t)o*128;
  float acc=0;
  for(int c=0;c<128;c++) acc+=xr[c]*wr[c];
  int hh=(o>>5)&3, d=o&31;
  if(o<128){
    float ss=acc*acc;
    #pragma unroll
    for(int m=1;m<32;m<<=1) ss+=__shfl_xor(ss,m);
    acc/=fmaxf(sqrtf(ss),1e-12f);
    kpb[(((size_t)b*4+hh)*64+p)*32+d]=acc;
  } else {
    vpb[(((size_t)b*4+hh)*64+p)*32+d]=acc;
  }
}

// ============ CPB MLP (verified) ============
__global__ __launch_bounds__(256) void cpb_kernel(const float* __restrict__ tbl,
  const float* __restrict__ w1, const float* __restrict__ b1,
  const float* __restrict__ w2, const float* __restrict__ b2, float* __restrict__ tout){
  int i=blockIdx.x;
  float c0=tbl[i*2], c1=tbl[i*2+1];
  int tid=threadIdx.x;
  float p0=0,p1=0,p2=0,p3=0;
  for(int j=tid;j<512;j+=256){
    float r=fmaxf(c0*w1[j*2]+c1*w1[j*2+1]+b1[j],0.0f);
    p0+=r*w2[j]; p1+=r*w2[512+j]; p2+=r*w2[1024+j]; p3+=r*w2[1536+j];
  }
  #pragma unroll
  for(int m=1;m<64;m<<=1){
    p0+=__shfl_xor(p0,m); p1+=__shfl_xor(p1,m);
    p2+=__shfl_xor(p2,m); p3+=__shfl_xor(p3,m);
  }
  __shared__ float red[4][4];
  int w=tid>>6;
  if((tid&63)==0){ red[w][0]=p0; red[w][1]=p1; red[w][2]=p2; red[w][3]=p3; }
  __syncthreads();
  if(tid<4)
    tout[(size_t)i*4+tid]=red[0][tid]+red[1][tid]+red[2][tid]+red[3][tid]+b2[tid];
}

// ============ attention v4: round-6 kernel + 8-token loop per wave + token-major kv ====
// block = 32 tokens (4 waves x 8-token loop), head = blockIdx.y.
// kp/vp staged ONCE per block (was: per 4 tokens). Per-token body identical to
// verified round-6 attn3; kv accessed token-major: kv_tm[np*256 + {0,128} + h*32+d].
__global__ __launch_bounds__(256) void attn4_kernel(
  const float* __restrict__ qs, const float* __restrict__ qn,
  const float* __restrict__ kv_tm, const float* __restrict__ kp,
  const float* __restrict__ vp, const float* __restrict__ tb,
  const int* __restrict__ rpi, const float* __restrict__ relb,
  const float* __restrict__ ltok, const float* __restrict__ lbias,
  ushort* __restrict__ mid){
  int n0=blockIdx.x*32, h=blockIdx.y, b=blockIdx.z;
  int wv=threadIdx.x>>6, lane=threadIdx.x&63;
  __shared__ float kp_s[64][33];
  __shared__ float vp_s[64][33];
  __shared__ float qs_s[4][32], qn_s[4][32];
  __shared__ float ap_sh[4][64];
  __shared__ float lm_sh[4][9];
  {
    size_t kb=((size_t)(b*4+h))*2048;   // 64 pool slots * 32 dims
    for(int i=threadIdx.x;i<2048;i+=256){
      kp_s[i>>5][i&31]=kp[kb+i];
      vp_s[i>>5][i&31]=vp[kb+i];
    }
  }
  __syncthreads();
  for(int ti=0;ti<8;ti++){
    int n=n0+wv*8+ti;
    int y=n>>6, x=n&63;
    if(lane<32) qs_s[wv][lane]=qs[((size_t)b*NTOK+n)*128+h*32+lane];
    else        qn_s[wv][lane-32]=qn[((size_t)b*NTOK+n)*128+h*32+(lane-32)];
    __syncthreads();
    // pool logit for slot p = lane (identical formula to round 6)
    float lp;
    {
      float s=0;
      #pragma unroll
      for(int d=0;d<32;d++) s+=qs_s[wv][d]*kp_s[lane][d];
      lp=s+tb[(size_t)rpi[(size_t)n*64+lane]*4+h];
    }
    bool lval=lane<9;
    float ll=0.0f;
    if(lval){
      int dy=lane/3-1, dx=lane%3-1;
      int yy=y+dy, xx=x+dx;
      float s=0;
      if(yy>=0&&yy<64&&xx>=0&&xx<64){
        int np=yy*64+xx;
        const float* kr=kv_tm+(size_t)np*256+h*32;
        #pragma unroll
        for(int d=0;d<32;d++) s+=qs_s[wv][d]*kr[d+(size_t)b*0];
        s+=0.0f;
        // batch offset folded below (kv_tm is per-batch indexed)
      }
      ll=s+relb[h*9+lane];
    }
    // NOTE: batch offset must be in np base — recompute properly:
    // (handled by kvb pointer below in PV; for K we redo with kvb)
    if(lval){
      int dy=lane/3-1, dx=lane%3-1;
      int yy=y+dy, xx=x+dx;
      float s=0;
      if(yy>=0&&yy<64&&xx>=0&&xx<64){
        size_t np=(size_t)b*NTOK+(size_t)(yy*64+xx);
        const float* kr=kv_tm+np*256+h*32;
        #pragma unroll
        for(int d=0;d<32;d++) s+=qs_s[wv][d]*kr[d];
      }
      ll=s+relb[h*9+lane];
    }
    float m=lp; if(lval) m=fmaxf(m,ll);
    #pragma unroll
    for(int o=1;o<64;o<<=1) m=fmaxf(m,__shfl_xor(m,o));
    float ep=expf(lp-m);
    float el=lval?expf(ll-m):0.0f;
    float ssum=ep+el;
    #pragma unroll
    for(int o=1;o<64;o<<=1) ssum+=__shfl_xor(ssum,o);
    float inv=1.0f/ssum;
    ap_sh[wv][lane]=ep*inv;
    if(lval){
      float lm=lbias[h*9+lane]+el*inv;
      #pragma unroll
      for(int d=0;d<32;d++) lm+=qn_s[wv][d]*ltok[(size_t)(h*32+d)*9+lane];
      lm_sh[wv][lane]=lm;
    }
    __syncthreads();
    if(lane<32){
      int d=lane;
      float acc=0;
      #pragma unroll
      for(int l=0;l<9;l++){
        int dy=l/3-1, dx=l%3-1;
        int yy=y+dy, xx=x+dx;
        if(yy>=0&&yy<64&&xx>=0&&xx<64){
          size_t np=(size_t)b*NTOK+(size_t)(yy*64+xx);
          acc+=lm_sh[wv][l]*kv_tm[np*256+128+h*32+d];
        }
      }
      #pragma unroll
      for(int p=0;p<64;p++) acc+=ap_sh[wv][p]*vp_s[p][d];
      mid[((size_t)b*NTOK+n)*128+h*32+d]=f2bf(acc);
    }
  }
}

// ============ MFMA GEMM: C[M,N]=A[M,K]@W[N,K]^T ; plain epilogues (verified) ============
// EPI 0: +bias, store f32 stride 682, guard col<Nreal   (fc1)
// EPI 1: +bias +resid, store f32 stride 128             (proj, fc2)
template<int KTILES,int EPI>
__global__ __launch_bounds__(256) void gemm_kernel(
  const ushort* __restrict__ A, const ushort* __restrict__ W,
  const float* __restrict__ bias, const float* __restrict__ resid,
  float* __restrict__ out, int Nreal){
  const int Kt=KTILES*128;
  int m0=blockIdx.x*128, n0=blockIdx.y*64;
  int tid=threadIdx.x;
  int wave=tid>>6, lane=tid&63;
  __shared__ ushort lA[128*128];
  __shared__ ushort lB[64*128];
  f32x4 acc[4][2]={};
  int wm=(wave>>1)*64, wn=(wave&1)*32;
  for(int kc=0;kc<KTILES;kc++){
    __syncthreads();
    #pragma unroll
    for(int it=0;it<8;it++){
      int id=it*256+tid;
      int kb=id&15, m=id>>4;
      uint4 v=*(const uint4*)(A+(size_t)(m0+m)*Kt+kc*128+kb*8);
      int byte=(m*256+kb*16)^((m&7)<<4);
      *(uint4*)((char*)lA+byte)=v;
    }
    #pragma unroll
    for(int it=0;it<4;it++){
      int id=it*256+tid;
      int kb=id&15, n=id>>4;
      uint4 v=*(const uint4*)(W+(size_t)(n0+n)*Kt+kc*128+kb*8);
      int byte=(n*256+kb*16)^((n&7)<<4);
      *(uint4*)((char*)lB+byte)=v;
    }
    __syncthreads();
    #pragma unroll
    for(int ks=0;ks<4;ks++){
      int kb=ks*4+(lane>>4);
      bfx8 bfr[2];
      #pragma unroll
      for(int nr=0;nr<2;nr++){
        int n=wn+nr*16+(lane&15);
        int byte=(n*256+kb*16)^((n&7)<<4);
        bfr[nr]=*(bfx8*)((char*)lB+byte);
      }
      #pragma unroll
      for(int mr=0;mr<4;mr++){
        int m=wm+mr*16+(lane&15);
        int byte=(m*256+kb*16)^((m&7)<<4);
        bfx8 afr=*(bfx8*)((char*)lA+byte);
        acc[mr][0]=__builtin_amdgcn_mfma_f32_16x16x32_bf16(afr,bfr[0],acc[mr][0],0,0,0);
        acc[mr][1]=__builtin_amdgcn_mfma_f32_16x16x32_bf16(afr,bfr[1],acc[mr][1],0,0,0);
      }
    }
  }
  int g=lane>>4, li=lane&15;
  #pragma unroll
  for(int mr=0;mr<4;mr++){
    #pragma unroll
    for(int r=0;r<4;r++){
      int row=m0+wm+mr*16+g*4+r;
      #pragma unroll
      for(int nr=0;nr<2;nr++){
        int col=n0+wn+nr*16+li;
        float v=acc[mr][nr][r];
        if constexpr(EPI==0){
          if(col<Nreal) out[(size_t)row*682+col]=v+bias[col];
        } else {
          out[(size_t)row*128+col]=v+bias[col]+resid[(size_t)row*128+col];
        }
      }
    }
  }
}

// ============ depthwise 3x3 + gelu*gate -> act_bf (tok,384 zero-padded) ============
__global__ __launch_bounds__(256) void dwconv_kernel(const float* __restrict__ u,
    const float* __restrict__ dww, const float* __restrict__ dwb, ushort* __restrict__ act){
  int c0=blockIdx.x*32;
  int cwReal=341-c0; if(cwReal>32) cwReal=32;
  int y0=blockIdx.y*2;
  int b=blockIdx.z;
  int tid=threadIdx.x;
  __shared__ float gsh[4][64][33];
  for(int it=0;it<32;it++){
    int idx=it*256+tid;
    int cc=idx&31;
    int px=(idx>>5)&63;
    int row=idx>>11;
    int yy=y0-1+row;
    float v=0.0f;
    if(yy>=0&&yy<64&&cc<cwReal)
      v=u[((size_t)b*NTOK+yy*64+px)*682+c0+cc];
    gsh[row][px][cc]=v;
  }
  __syncthreads();
  int cc=tid&31, pxb=tid>>5;
  int c=c0+cc;
  if(c>=384) return;
  if(cc<cwReal){
    float w0=dww[c*9+0],w1=dww[c*9+1],w2=dww[c*9+2],
          w3=dww[c*9+3],w4=dww[c*9+4],w5=dww[c*9+5],
          w6=dww[c*9+6],w7=dww[c*9+7],w8=dww[c*9+8];
    float bias=dwb[c];
    for(int ty=0;ty<2;ty++){
      for(int pxi=0;pxi<8;pxi++){
        int px=pxi*8+pxb;
        float ss=0.0f;
        if(px>0){ ss+=gsh[ty][px-1][cc]*w0+gsh[ty+1][px-1][cc]*w3+gsh[ty+2][px-1][cc]*w6; }
        ss+=gsh[ty][px][cc]*w1+gsh[ty+1][px][cc]*w4+gsh[ty+2][px][cc]*w7;
        if(px<63){ ss+=gsh[ty][px+1][cc]*w2+gsh[ty+1][px+1][cc]*w5+gsh[ty+2][px+1][cc]*w8; }
        float z=ss+bias;
        int nn=(y0+ty)*64+px;
        float gate=u[((size_t)b*NTOK+nn)*682+341+c];
        act[((size_t)b*NTOK+nn)*384+c]=f2bf(geluf(z)*gate);
      }
    }
  } else {
    for(int ty=0;ty<2;ty++)
      for(int pxi=0;pxi<8;pxi++){
        int px=pxi*8+pxb;
        int nn=(y0+ty)*64+px;
        act[((size_t)b*NTOK+nn)*384+c]=0;
      }
  }
}

extern "C" void kernel_launch(void* const* d_in, const int* in_sizes, int n_in,
                              void* d_out, int out_size, void* d_ws, size_t ws_size,
                              hipStream_t stream){
  const float* x     =(const float*)d_in[0];
  const float* n1g   =(const float*)d_in[1];
  const float* n1b   =(const float*)d_in[2];
  const float* qw    =(const float*)d_in[3];
  const float* kvw   =(const float*)d_in[4];
  const float* temp  =(const float*)d_in[5];
  const float* qemb  =(const float*)d_in[6];
  const float* relb  =(const float*)d_in[7];
  const float* ltok  =(const float*)d_in[8];
  const float* lbias =(const float*)d_in[9];
  const float* srw   =(const float*)d_in[10];
  const float* srb   =(const float*)d_in[11];
  const float* npg   =(const float*)d_in[12];
  const float* npb   =(const float*)d_in[13];
  const float* cpb1w =(const float*)d_in[14];
  const float* cpb1b =(const float*)d_in[15];
  const float* cpb2w =(const float*)d_in[16];
  const float* cpb2b =(const float*)d_in[17];
  const float* projw =(const float*)d_in[18];
  const float* projb =(const float*)d_in[19];
  const float* n2g   =(const float*)d_in[20];
  const float* n2b   =(const float*)d_in[21];
  const float* fc1w  =(const float*)d_in[22];
  const float* fc1b  =(const float*)d_in[23];
  const float* dww   =(const float*)d_in[24];
  const float* dwb   =(const float*)d_in[25];
  const float* fc2w  =(const float*)d_in[26];
  const float* fc2b  =(const float*)d_in[27];
  const float* ctab  =(const float*)d_in[28];
  const float* seqs  =(const float*)d_in[29];
  const int*   rpi   =(const int*)d_in[30];

  char* base=(char*)d_ws;
  float*  h_f32 =(float*)(base+0);            // 16.8 MB (dead after srpool)
  float*  qs_b  =(float*)(base+16777216);     // 16.8 MB (dead after attn)
  float*  qn_b  =(float*)(base+33554432);     // 16.8 MB (dead after attn)
  float*  kv_tm =(float*)(base+50331648);     // 33.5 MB token-major (dead after attn)
  ushort* mid_bf=(ushort*)(base+83886080);    // 8.4 MB (dead after proj)
  float*  x2    =(float*)(base+92274688);     // 16.8 MB (live until fc2)
  ushort* h2_bf =(ushort*)(base+109051904);   // 8.4 MB (dead after fc1)
  float*  u_buf =(float*)(base+0);            // 89.4 MB overlay of h..mid (all dead)
  ushort* act_bf=(ushort*)(base+109051904);   // 25.2 MB overlay of h2 (dead)
  float*  xipre =(float*)(base+142606336);
  float*  xi    =(float*)(base+142868480);
  float*  kp    =(float*)(base+143130624);
  float*  vp    =(float*)(base+143392768);
  float*  tbuf  =(float*)(base+143654912);
  ushort* pwb   =(ushort*)(base+143671296);
  ushort* f1wb  =(ushort*)(base+143704064);
  ushort* f2wb  =(ushort*)(base+143884288);   // ends 143982592

  convw_kernel<<<608,256,0,stream>>>(projw,fc1w,fc2w,pwb,f1wb,f2wb);
  ln_f32_kernel<<<32768,128,0,stream>>>(x,n1g,n1b,h_f32);
  qproj_kernel<<<4096,128,0,stream>>>(h_f32,qw,qemb,temp,seqs,qs_b,qn_b);
  kvproj_kernel<<<4096,256,0,stream>>>(h_f32,kvw,kv_tm);
  srpool_kernel<<<512,128,0,stream>>>(h_f32,srw,srb,xipre);
  ln_f32_kernel<<<512,128,0,stream>>>(xipre,npg,npb,xi);
  kvp_kernel<<<512,256,0,stream>>>(xi,kvw,kp,vp);
  cpb_kernel<<<1024,256,0,stream>>>(ctab,cpb1w,cpb1b,cpb2w,cpb2b,tbuf);
  attn4_kernel<<<dim3(128,4,8),256,0,stream>>>(qs_b,qn_b,kv_tm,kp,vp,tbuf,rpi,relb,ltok,lbias,mid_bf);
  gemm_kernel<1,1><<<dim3(256,2),256,0,stream>>>(mid_bf,pwb,projb,x,x2,128);
  ln_bf_kernel<<<32768,128,0,stream>>>(x2,n2g,n2b,h2_bf);
  gemm_kernel<1,0><<<dim3(256,11),256,0,stream>>>(h2_bf,f1wb,fc1b,nullptr,u_buf,682);
  dwconv_kernel<<<dim3(12,32,8),256,0,stream>>>(u_buf,dww,dwb,act_bf);
  gemm_kernel<3,1><<<dim3(256,2),256,0,stream>>>(act_bf,f2wb,fc2b,x2,(float*)d_out,128);
}

// Round 8
// 685.647 us; speedup vs baseline: 1.2604x; 1.2604x over previous
//
#include <hip/hip_runtime.h>
#include <hip/hip_bf16.h>
#include <math.h>

#define NTOK 4096
#define CDIM 128

typedef __attribute__((ext_vector_type(4))) float f32x4;
typedef __attribute__((ext_vector_type(8))) short bfx8;

__device__ __forceinline__ float geluf(float z){
  return 0.5f*z*(1.0f+erff(z*0.70710678118654752440f));
}
__device__ __forceinline__ float softplusf(float x){
  return (x>20.0f)?x:log1pf(expf(x));
}
__device__ __forceinline__ ushort f2bf(float f){
  __hip_bfloat16 h=__float2bfloat16(f);
  return *reinterpret_cast<ushort*>(&h);
}

// ============ weight conversion to bf16 (+padding): proj, fc1, fc2 only ============
__global__ __launch_bounds__(256) void convw_kernel(
  const float* __restrict__ projw, const float* __restrict__ fc1w,
  const float* __restrict__ fc2w,
  ushort* __restrict__ pwb, ushort* __restrict__ f1wb, ushort* __restrict__ f2wb){
  int id=blockIdx.x*256+threadIdx.x;
  if(id<16384) pwb[id]=f2bf(projw[id]);
  else if(id<106496){ int t=id-16384; int nn=t>>7,k=t&127;
    f1wb[t]=f2bf(nn<682? fc1w[nn*128+k] : 0.0f); }
  else if(id<155648){ int t=id-106496; int nn=t/384,k=t-nn*384;
    f2wb[t]=f2bf(k<341? fc2w[nn*341+k] : 0.0f); }
}

// ============ LayerNorm fp32 out ============
__global__ __launch_bounds__(128) void ln_f32_kernel(const float* __restrict__ in,
    const float* __restrict__ g, const float* __restrict__ bb, float* __restrict__ out){
  int t=blockIdx.x, c=threadIdx.x;
  float v=in[(size_t)t*CDIM+c];
  __shared__ float red[2];
  float s=v;
  #pragma unroll
  for(int m=1;m<64;m<<=1) s+=__shfl_xor(s,m);
  if((c&63)==0) red[c>>6]=s;
  __syncthreads();
  float mean=(red[0]+red[1])*(1.0f/CDIM);
  float d=v-mean;
  __syncthreads();
  float s2=d*d;
  #pragma unroll
  for(int m=1;m<64;m<<=1) s2+=__shfl_xor(s2,m);
  if((c&63)==0) red[c>>6]=s2;
  __syncthreads();
  float var=(red[0]+red[1])*(1.0f/CDIM);
  out[(size_t)t*CDIM+c]=d*rsqrtf(var+1e-5f)*g[c]+bb[c];
}

// ============ LayerNorm bf16 out ============
__global__ __launch_bounds__(128) void ln_bf_kernel(const float* __restrict__ in,
    const float* __restrict__ g, const float* __restrict__ bb, ushort* __restrict__ out){
  int t=blockIdx.x, c=threadIdx.x;
  float v=in[(size_t)t*CDIM+c];
  __shared__ float red[2];
  float s=v;
  #pragma unroll
  for(int m=1;m<64;m<<=1) s+=__shfl_xor(s,m);
  if((c&63)==0) red[c>>6]=s;
  __syncthreads();
  float mean=(red[0]+red[1])*(1.0f/CDIM);
  float d=v-mean;
  __syncthreads();
  float s2=d*d;
  #pragma unroll
  for(int m=1;m<64;m<<=1) s2+=__shfl_xor(s2,m);
  if((c&63)==0) red[c>>6]=s2;
  __syncthreads();
  float var=(red[0]+red[1])*(1.0f/CDIM);
  out[(size_t)t*CDIM+c]=f2bf(d*rsqrtf(var+1e-5f)*g[c]+bb[c]);
}

// ============ q proj + l2 norm + scale (verified, fp32) ============
__global__ __launch_bounds__(128) void qproj_kernel(const float* __restrict__ h,
  const float* __restrict__ qw, const float* __restrict__ qemb,
  const float* __restrict__ temp, const float* __restrict__ seqs,
  float* __restrict__ qsout, float* __restrict__ qnout){
  int t0=blockIdx.x*8;
  int o=threadIdx.x;
  __shared__ float hr[8][128];
  for(int i=o;i<1024;i+=128) hr[i>>7][i&127]=h[(size_t)t0*128+i];
  __syncthreads();
  const float* wr=qw+(size_t)o*128;
  float a[8]={0,0,0,0,0,0,0,0};
  for(int c=0;c<128;c++){
    float wv=wr[c];
    #pragma unroll
    for(int tt=0;tt<8;tt++) a[tt]+=hr[tt][c]*wv;
  }
  int hh=o>>5, d=o&31;
  float emb=qemb[hh*32+d];
  float scale=softplusf(temp[hh])*seqs[0];
  #pragma unroll
  for(int tt=0;tt<8;tt++){
    float ss=a[tt]*a[tt];
    #pragma unroll
    for(int m=1;m<32;m<<=1) ss+=__shfl_xor(ss,m);
    float qnv=a[tt]/fmaxf(sqrtf(ss),1e-12f);
    qnout[(size_t)(t0+tt)*128+o]=qnv;
    qsout[(size_t)(t0+tt)*128+o]=(qnv+emb)*scale;
  }
}

// ============ kv proj (verified, round-7) -> TOKEN-major (B,N,256) ============
__global__ __launch_bounds__(256) void kvproj_kernel(const float* __restrict__ h,
  const float* __restrict__ kvw, float* __restrict__ kv_tm){
  int t0=blockIdx.x*8;
  int tid=threadIdx.x;
  __shared__ float hr[8][128];
  for(int i=tid;i<1024;i+=256) hr[i>>7][i&127]=h[(size_t)t0*128+i];
  __syncthreads();
  const float* wr=kvw+(size_t)tid*128;
  float a[8]={0,0,0,0,0,0,0,0};
  for(int c=0;c<128;c++){
    float wv=wr[c];
    #pragma unroll
    for(int tt=0;tt<8;tt++) a[tt]+=hr[tt][c]*wv;
  }
  #pragma unroll
  for(int tt=0;tt<8;tt++){
    float v=a[tt];
    if(tid<128){
      float ss=v*v;
      #pragma unroll
      for(int m=1;m<32;m<<=1) ss+=__shfl_xor(ss,m);
      v/=fmaxf(sqrtf(ss),1e-12f);
    }
    kv_tm[(size_t)(t0+tt)*256+tid]=v;
  }
}

// ============ sr 1x1 conv + gelu + 8x8 avg pool (verified) ============
__global__ __launch_bounds__(128) void srpool_kernel(const float* __restrict__ h,
  const float* __restrict__ srw, const float* __restrict__ srb, float* __restrict__ xipre){
  int bp=blockIdx.x;
  int b=bp>>6, pp=bp&63;
  int py=pp>>3, px=pp&7;
  int o=threadIdx.x;
  __shared__ float hr[64][128];
  for(int i=0;i<64;i++){
    int yy=py*8+(i>>3), xx=px*8+(i&7);
    hr[i][o]=h[((size_t)b*NTOK+yy*64+xx)*128+o];
  }
  __syncthreads();
  const float* wr=srw+(size_t)o*128;
  float bias=srb[o];
  float acc=0;
  for(int i=0;i<64;i++){
    float s=bias;
    for(int c=0;c<128;c++) s+=hr[i][c]*wr[c];
    acc+=geluf(s);
  }
  xipre[(size_t)bp*128+o]=acc*(1.0f/64.0f);
}

// ============ pooled kv proj (verified) ============
__global__ __launch_bounds__(256) void kvp_kernel(const float* __restrict__ xi,
  const float* __restrict__ kvw, float* __restrict__ kpb, float* __restrict__ vpb){
  int bp=blockIdx.x;
  int b=bp>>6, p=bp&63;
  int o=threadIdx.x;
  __shared__ float xr[128];
  if(o<128) xr[o]=xi[(size_t)bp*128+o];
  __syncthreads();
  const float* wr=kvw+(size_t)o*128;
  float acc=0;
  for(int c=0;c<128;c++) acc+=xr[c]*wr[c];
  int hh=(o>>5)&3, d=o&31;
  if(o<128){
    float ss=acc*acc;
    #pragma unroll
    for(int m=1;m<32;m<<=1) ss+=__shfl_xor(ss,m);
    acc/=fmaxf(sqrtf(ss),1e-12f);
    kpb[(((size_t)b*4+hh)*64+p)*32+d]=acc;
  } else {
    vpb[(((size_t)b*4+hh)*64+p)*32+d]=acc;
  }
}

// ============ CPB MLP (verified) ============
__global__ __launch_bounds__(256) void cpb_kernel(const float* __restrict__ tbl,
  const float* __restrict__ w1, const float* __restrict__ b1,
  const float* __restrict__ w2, const float* __restrict__ b2, float* __restrict__ tout){
  int i=blockIdx.x;
  float c0=tbl[i*2], c1=tbl[i*2+1];
  int tid=threadIdx.x;
  float p0=0,p1=0,p2=0,p3=0;
  for(int j=tid;j<512;j+=256){
    float r=fmaxf(c0*w1[j*2]+c1*w1[j*2+1]+b1[j],0.0f);
    p0+=r*w2[j]; p1+=r*w2[512+j]; p2+=r*w2[1024+j]; p3+=r*w2[1536+j];
  }
  #pragma unroll
  for(int m=1;m<64;m<<=1){
    p0+=__shfl_xor(p0,m); p1+=__shfl_xor(p1,m);
    p2+=__shfl_xor(p2,m); p3+=__shfl_xor(p3,m);
  }
  __shared__ float red[4][4];
  int w=tid>>6;
  if((tid&63)==0){ red[w][0]=p0; red[w][1]=p1; red[w][2]=p2; red[w][3]=p3; }
  __syncthreads();
  if(tid<4)
    tout[(size_t)i*4+tid]=red[0][tid]+red[1][tid]+red[2][tid]+red[3][tid]+b2[tid];
}

// ============ attention v3b: verified round-6 attn3 + token-major kv indexing ============
// block = 4 tokens (wave = token), head = blockIdx.y. Only change vs round-6 attn3:
// kv reads use kv_tm[(b*NTOK+np)*256 + {0,128} + h*32+d] (was channel-major).
__global__ __launch_bounds__(256) void attn3b_kernel(
  const float* __restrict__ qs, const float* __restrict__ qn,
  const float* __restrict__ kv_tm, const float* __restrict__ kp,
  const float* __restrict__ vp, const float* __restrict__ tb,
  const int* __restrict__ rpi, const float* __restrict__ relb,
  const float* __restrict__ ltok, const float* __restrict__ lbias,
  ushort* __restrict__ mid){
  int n0=blockIdx.x*4, h=blockIdx.y, b=blockIdx.z;
  int tt=threadIdx.x>>6, lane=threadIdx.x&63;
  int n=n0+tt;
  int y=n>>6, x=n&63;
  __shared__ float kp_s[64][33];
  __shared__ float vp_s[64][33];
  __shared__ float qs_s[4][32], qn_s[4][32];
  __shared__ float ap_sh[4][64];
  __shared__ float lm_sh[4][9];
  {
    size_t kb=((size_t)(b*4+h))*2048;   // 64 pool slots * 32 dims
    for(int i=threadIdx.x;i<2048;i+=256){
      kp_s[i>>5][i&31]=kp[kb+i];
      vp_s[i>>5][i&31]=vp[kb+i];
    }
  }
  if(lane<32) qs_s[tt][lane]=qs[((size_t)b*NTOK+n)*128+h*32+lane];
  else        qn_s[tt][lane-32]=qn[((size_t)b*NTOK+n)*128+h*32+(lane-32)];
  __syncthreads();
  // pool logit for slot p = lane
  float lp;
  {
    float s=0;
    #pragma unroll
    for(int d=0;d<32;d++) s+=qs_s[tt][d]*kp_s[lane][d];
    lp=s+tb[(size_t)rpi[(size_t)n*64+lane]*4+h];
  }
  bool lval=lane<9;
  float ll=0.0f;
  if(lval){
    int dy=lane/3-1, dx=lane%3-1;
    int yy=y+dy, xx=x+dx;
    float s=0;
    if(yy>=0&&yy<64&&xx>=0&&xx<64){
      const float* kr=kv_tm+((size_t)b*NTOK+(size_t)(yy*64+xx))*256+h*32;
      #pragma unroll
      for(int d=0;d<32;d++) s+=qs_s[tt][d]*kr[d];
    }
    ll=s+relb[h*9+lane];
  }
  float m=lp; if(lval) m=fmaxf(m,ll);
  #pragma unroll
  for(int o=1;o<64;o<<=1) m=fmaxf(m,__shfl_xor(m,o));
  float ep=expf(lp-m);
  float el=lval?expf(ll-m):0.0f;
  float ssum=ep+el;
  #pragma unroll
  for(int o=1;o<64;o<<=1) ssum+=__shfl_xor(ssum,o);
  float inv=1.0f/ssum;
  ap_sh[tt][lane]=ep*inv;
  if(lval){
    float lm=lbias[h*9+lane]+el*inv;
    #pragma unroll
    for(int d=0;d<32;d++) lm+=qn_s[tt][d]*ltok[(size_t)(h*32+d)*9+lane];
    lm_sh[tt][lane]=lm;
  }
  __syncthreads();
  if(lane<32){
    int d=lane;
    float acc=0;
    #pragma unroll
    for(int l=0;l<9;l++){
      int dy=l/3-1, dx=l%3-1;
      int yy=y+dy, xx=x+dx;
      if(yy>=0&&yy<64&&xx>=0&&xx<64)
        acc+=lm_sh[tt][l]*kv_tm[((size_t)b*NTOK+(size_t)(yy*64+xx))*256+128+h*32+d];
    }
    #pragma unroll
    for(int p=0;p<64;p++) acc+=ap_sh[tt][p]*vp_s[p][d];
    mid[((size_t)b*NTOK+n)*128+h*32+d]=f2bf(acc);
  }
}

// ============ MFMA GEMM: C[M,N]=A[M,K]@W[N,K]^T ; plain epilogues (verified) ============
// EPI 0: +bias, store f32 stride 682, guard col<Nreal   (fc1)
// EPI 1: +bias +resid, store f32 stride 128             (proj, fc2)
template<int KTILES,int EPI>
__global__ __launch_bounds__(256) void gemm_kernel(
  const ushort* __restrict__ A, const ushort* __restrict__ W,
  const float* __restrict__ bias, const float* __restrict__ resid,
  float* __restrict__ out, int Nreal){
  const int Kt=KTILES*128;
  int m0=blockIdx.x*128, n0=blockIdx.y*64;
  int tid=threadIdx.x;
  int wave=tid>>6, lane=tid&63;
  __shared__ ushort lA[128*128];
  __shared__ ushort lB[64*128];
  f32x4 acc[4][2]={};
  int wm=(wave>>1)*64, wn=(wave&1)*32;
  for(int kc=0;kc<KTILES;kc++){
    __syncthreads();
    #pragma unroll
    for(int it=0;it<8;it++){
      int id=it*256+tid;
      int kb=id&15, m=id>>4;
      uint4 v=*(const uint4*)(A+(size_t)(m0+m)*Kt+kc*128+kb*8);
      int byte=(m*256+kb*16)^((m&7)<<4);
      *(uint4*)((char*)lA+byte)=v;
    }
    #pragma unroll
    for(int it=0;it<4;it++){
      int id=it*256+tid;
      int kb=id&15, n=id>>4;
      uint4 v=*(const uint4*)(W+(size_t)(n0+n)*Kt+kc*128+kb*8);
      int byte=(n*256+kb*16)^((n&7)<<4);
      *(uint4*)((char*)lB+byte)=v;
    }
    __syncthreads();
    #pragma unroll
    for(int ks=0;ks<4;ks++){
      int kb=ks*4+(lane>>4);
      bfx8 bfr[2];
      #pragma unroll
      for(int nr=0;nr<2;nr++){
        int n=wn+nr*16+(lane&15);
        int byte=(n*256+kb*16)^((n&7)<<4);
        bfr[nr]=*(bfx8*)((char*)lB+byte);
      }
      #pragma unroll
      for(int mr=0;mr<4;mr++){
        int m=wm+mr*16+(lane&15);
        int byte=(m*256+kb*16)^((m&7)<<4);
        bfx8 afr=*(bfx8*)((char*)lA+byte);
        acc[mr][0]=__builtin_amdgcn_mfma_f32_16x16x32_bf16(afr,bfr[0],acc[mr][0],0,0,0);
        acc[mr][1]=__builtin_amdgcn_mfma_f32_16x16x32_bf16(afr,bfr[1],acc[mr][1],0,0,0);
      }
    }
  }
  int g=lane>>4, li=lane&15;
  #pragma unroll
  for(int mr=0;mr<4;mr++){
    #pragma unroll
    for(int r=0;r<4;r++){
      int row=m0+wm+mr*16+g*4+r;
      #pragma unroll
      for(int nr=0;nr<2;nr++){
        int col=n0+wn+nr*16+li;
        float v=acc[mr][nr][r];
        if constexpr(EPI==0){
          if(col<Nreal) out[(size_t)row*682+col]=v+bias[col];
        } else {
          out[(size_t)row*128+col]=v+bias[col]+resid[(size_t)row*128+col];
        }
      }
    }
  }
}

// ============ depthwise 3x3 + gelu*gate -> act_bf (tok,384 zero-padded) ============
__global__ __launch_bounds__(256) void dwconv_kernel(const float* __restrict__ u,
    const float* __restrict__ dww, const float* __restrict__ dwb, ushort* __restrict__ act){
  int c0=blockIdx.x*32;
  int cwReal=341-c0; if(cwReal>32) cwReal=32;
  int y0=blockIdx.y*2;
  int b=blockIdx.z;
  int tid=threadIdx.x;
  __shared__ float gsh[4][64][33];
  for(int it=0;it<32;it++){
    int idx=it*256+tid;
    int cc=idx&31;
    int px=(idx>>5)&63;
    int row=idx>>11;
    int yy=y0-1+row;
    float v=0.0f;
    if(yy>=0&&yy<64&&cc<cwReal)
      v=u[((size_t)b*NTOK+yy*64+px)*682+c0+cc];
    gsh[row][px][cc]=v;
  }
  __syncthreads();
  int cc=tid&31, pxb=tid>>5;
  int c=c0+cc;
  if(c>=384) return;
  if(cc<cwReal){
    float w0=dww[c*9+0],w1=dww[c*9+1],w2=dww[c*9+2],
          w3=dww[c*9+3],w4=dww[c*9+4],w5=dww[c*9+5],
          w6=dww[c*9+6],w7=dww[c*9+7],w8=dww[c*9+8];
    float bias=dwb[c];
    for(int ty=0;ty<2;ty++){
      for(int pxi=0;pxi<8;pxi++){
        int px=pxi*8+pxb;
        float ss=0.0f;
        if(px>0){ ss+=gsh[ty][px-1][cc]*w0+gsh[ty+1][px-1][cc]*w3+gsh[ty+2][px-1][cc]*w6; }
        ss+=gsh[ty][px][cc]*w1+gsh[ty+1][px][cc]*w4+gsh[ty+2][px][cc]*w7;
        if(px<63){ ss+=gsh[ty][px+1][cc]*w2+gsh[ty+1][px+1][cc]*w5+gsh[ty+2][px+1][cc]*w8; }
        float z=ss+bias;
        int nn=(y0+ty)*64+px;
        float gate=u[((size_t)b*NTOK+nn)*682+341+c];
        act[((size_t)b*NTOK+nn)*384+c]=f2bf(geluf(z)*gate);
      }
    }
  } else {
    for(int ty=0;ty<2;ty++)
      for(int pxi=0;pxi<8;pxi++){
        int px=pxi*8+pxb;
        int nn=(y0+ty)*64+px;
        act[((size_t)b*NTOK+nn)*384+c]=0;
      }
  }
}

extern "C" void kernel_launch(void* const* d_in, const int* in_sizes, int n_in,
                              void* d_out, int out_size, void* d_ws, size_t ws_size,
                              hipStream_t stream){
  const float* x     =(const float*)d_in[0];
  const float* n1g   =(const float*)d_in[1];
  const float* n1b   =(const float*)d_in[2];
  const float* qw    =(const float*)d_in[3];
  const float* kvw   =(const float*)d_in[4];
  const float* temp  =(const float*)d_in[5];
  const float* qemb  =(const float*)d_in[6];
  const float* relb  =(const float*)d_in[7];
  const float* ltok  =(const float*)d_in[8];
  const float* lbias =(const float*)d_in[9];
  const float* srw   =(const float*)d_in[10];
  const float* srb   =(const float*)d_in[11];
  const float* npg   =(const float*)d_in[12];
  const float* npb   =(const float*)d_in[13];
  const float* cpb1w =(const float*)d_in[14];
  const float* cpb1b =(const float*)d_in[15];
  const float* cpb2w =(const float*)d_in[16];
  const float* cpb2b =(const float*)d_in[17];
  const float* projw =(const float*)d_in[18];
  const float* projb =(const float*)d_in[19];
  const float* n2g   =(const float*)d_in[20];
  const float* n2b   =(const float*)d_in[21];
  const float* fc1w  =(const float*)d_in[22];
  const float* fc1b  =(const float*)d_in[23];
  const float* dww   =(const float*)d_in[24];
  const float* dwb   =(const float*)d_in[25];
  const float* fc2w  =(const float*)d_in[26];
  const float* fc2b  =(const float*)d_in[27];
  const float* ctab  =(const float*)d_in[28];
  const float* seqs  =(const float*)d_in[29];
  const int*   rpi   =(const int*)d_in[30];

  char* base=(char*)d_ws;
  float*  h_f32 =(float*)(base+0);            // 16.8 MB (dead after srpool)
  float*  qs_b  =(float*)(base+16777216);     // 16.8 MB (dead after attn)
  float*  qn_b  =(float*)(base+33554432);     // 16.8 MB (dead after attn)
  float*  kv_tm =(float*)(base+50331648);     // 33.5 MB token-major (dead after attn)
  ushort* mid_bf=(ushort*)(base+83886080);    // 8.4 MB (dead after proj)
  float*  x2    =(float*)(base+92274688);     // 16.8 MB (live until fc2)
  ushort* h2_bf =(ushort*)(base+109051904);   // 8.4 MB (dead after fc1)
  float*  u_buf =(float*)(base+0);            // 89.4 MB overlay of h..mid (all dead)
  ushort* act_bf=(ushort*)(base+109051904);   // 25.2 MB overlay of h2 (dead)
  float*  xipre =(float*)(base+142606336);
  float*  xi    =(float*)(base+142868480);
  float*  kp    =(float*)(base+143130624);
  float*  vp    =(float*)(base+143392768);
  float*  tbuf  =(float*)(base+143654912);
  ushort* pwb   =(ushort*)(base+143671296);
  ushort* f1wb  =(ushort*)(base+143704064);
  ushort* f2wb  =(ushort*)(base+143884288);   // ends 143982592

  convw_kernel<<<608,256,0,stream>>>(projw,fc1w,fc2w,pwb,f1wb,f2wb);
  ln_f32_kernel<<<32768,128,0,stream>>>(x,n1g,n1b,h_f32);
  qproj_kernel<<<4096,128,0,stream>>>(h_f32,qw,qemb,temp,seqs,qs_b,qn_b);
  kvproj_kernel<<<4096,256,0,stream>>>(h_f32,kvw,kv_tm);
  srpool_kernel<<<512,128,0,stream>>>(h_f32,srw,srb,xipre);
  ln_f32_kernel<<<512,128,0,stream>>>(xipre,npg,npb,xi);
  kvp_kernel<<<512,256,0,stream>>>(xi,kvw,kp,vp);
  cpb_kernel<<<1024,256,0,stream>>>(ctab,cpb1w,cpb1b,cpb2w,cpb2b,tbuf);
  attn3b_kernel<<<dim3(1024,4,8),256,0,stream>>>(qs_b,qn_b,kv_tm,kp,vp,tbuf,rpi,relb,ltok,lbias,mid_bf);
  gemm_kernel<1,1><<<dim3(256,2),256,0,stream>>>(mid_bf,pwb,projb,x,x2,128);
  ln_bf_kernel<<<32768,128,0,stream>>>(x2,n2g,n2b,h2_bf);
  gemm_kernel<1,0><<<dim3(256,11),256,0,stream>>>(h2_bf,f1wb,fc1b,nullptr,u_buf,682);
  dwconv_kernel<<<dim3(12,32,8),256,0,stream>>>(u_buf,dww,dwb,act_bf);
  gemm_kernel<3,1><<<dim3(256,2),256,0,stream>>>(act_bf,f2wb,fc2b,x2,(float*)d_out,128);
}

// Round 9
// 579.814 us; speedup vs baseline: 1.4904x; 1.1825x over previous
//
#include <hip/hip_runtime.h>
#include <hip/hip_bf16.h>
#include <math.h>

#define NTOK 4096
#define CDIM 128

typedef __attribute__((ext_vector_type(4))) float f32x4;
typedef __attribute__((ext_vector_type(8))) short bfx8;

__device__ __forceinline__ float geluf(float z){
  return 0.5f*z*(1.0f+erff(z*0.70710678118654752440f));
}
__device__ __forceinline__ float softplusf(float x){
  return (x>20.0f)?x:log1pf(expf(x));
}
__device__ __forceinline__ ushort f2bf(float f){
  __hip_bfloat16 h=__float2bfloat16(f);
  return *reinterpret_cast<ushort*>(&h);
}

// ============ weight conversion to bf16 (+padding): all six GEMM weights ============
__global__ __launch_bounds__(256) void convw_kernel(
  const float* __restrict__ qw, const float* __restrict__ kvw,
  const float* __restrict__ srw, const float* __restrict__ projw,
  const float* __restrict__ fc1w, const float* __restrict__ fc2w,
  ushort* __restrict__ qwb, ushort* __restrict__ kvwb,
  ushort* __restrict__ srwb, ushort* __restrict__ pwb,
  ushort* __restrict__ f1wb, ushort* __restrict__ f2wb){
  int id=blockIdx.x*256+threadIdx.x;
  if(id<16384) qwb[id]=f2bf(qw[id]);
  else if(id<49152){ int t=id-16384; kvwb[t]=f2bf(kvw[t]); }
  else if(id<65536){ int t=id-49152; srwb[t]=f2bf(srw[t]); }
  else if(id<81920){ int t=id-65536; pwb[t]=f2bf(projw[t]); }
  else if(id<172032){ int t=id-81920; int nn=t>>7,k=t&127;
    f1wb[t]=f2bf(nn<682? fc1w[nn*128+k] : 0.0f); }
  else if(id<221184){ int t=id-172032; int nn=t/384,k=t-nn*384;
    f2wb[t]=f2bf(k<341? fc2w[nn*341+k] : 0.0f); }
}

// ============ LayerNorm fp32 out (verified) ============
__global__ __launch_bounds__(128) void ln_f32_kernel(const float* __restrict__ in,
    const float* __restrict__ g, const float* __restrict__ bb, float* __restrict__ out){
  int t=blockIdx.x, c=threadIdx.x;
  float v=in[(size_t)t*CDIM+c];
  __shared__ float red[2];
  float s=v;
  #pragma unroll
  for(int m=1;m<64;m<<=1) s+=__shfl_xor(s,m);
  if((c&63)==0) red[c>>6]=s;
  __syncthreads();
  float mean=(red[0]+red[1])*(1.0f/CDIM);
  float d=v-mean;
  __syncthreads();
  float s2=d*d;
  #pragma unroll
  for(int m=1;m<64;m<<=1) s2+=__shfl_xor(s2,m);
  if((c&63)==0) red[c>>6]=s2;
  __syncthreads();
  float var=(red[0]+red[1])*(1.0f/CDIM);
  out[(size_t)t*CDIM+c]=d*rsqrtf(var+1e-5f)*g[c]+bb[c];
}

// ============ LayerNorm bf16 out (verified) ============
__global__ __launch_bounds__(128) void ln_bf_kernel(const float* __restrict__ in,
    const float* __restrict__ g, const float* __restrict__ bb, ushort* __restrict__ out){
  int t=blockIdx.x, c=threadIdx.x;
  float v=in[(size_t)t*CDIM+c];
  __shared__ float red[2];
  float s=v;
  #pragma unroll
  for(int m=1;m<64;m<<=1) s+=__shfl_xor(s,m);
  if((c&63)==0) red[c>>6]=s;
  __syncthreads();
  float mean=(red[0]+red[1])*(1.0f/CDIM);
  float d=v-mean;
  __syncthreads();
  float s2=d*d;
  #pragma unroll
  for(int m=1;m<64;m<<=1) s2+=__shfl_xor(s2,m);
  if((c&63)==0) red[c>>6]=s2;
  __syncthreads();
  float var=(red[0]+red[1])*(1.0f/CDIM);
  out[(size_t)t*CDIM+c]=f2bf(d*rsqrtf(var+1e-5f)*g[c]+bb[c]);
}

// ============ MFMA GEMM: C[M,N]=A[M,K]@W[N,K]^T ============
// EPI 0: +bias, store f32 stride 682, guard col<Nreal       (fc1)
// EPI 1: +bias +resid, store f32 stride 128                 (proj, fc2)
// EPI 2: gelu(v+bias), store f32 stride 128                 (sr 1x1)
// EPI 3: per-head l2norm -> qn; qs=(qn+emb)*softplus*seq    (qproj)
// EPI 4: cols<128 per-head l2norm, store f32 stride 256     (kvproj -> kv_tm)
template<int KTILES,int EPI>
__global__ __launch_bounds__(256) void gemm_kernel(
  const ushort* __restrict__ A, const ushort* __restrict__ W,
  const float* __restrict__ bias, const float* __restrict__ resid,
  float* __restrict__ out, float* __restrict__ out2, int Nreal,
  const float* __restrict__ qemb, const float* __restrict__ temp,
  const float* __restrict__ seqs){
  const int Kt=KTILES*128;
  int m0=blockIdx.x*128, n0=blockIdx.y*64;
  int tid=threadIdx.x;
  int wave=tid>>6, lane=tid&63;
  __shared__ ushort lA[128*128];
  __shared__ ushort lB[64*128];
  f32x4 acc[4][2]={};
  int wm=(wave>>1)*64, wn=(wave&1)*32;
  for(int kc=0;kc<KTILES;kc++){
    __syncthreads();
    #pragma unroll
    for(int it=0;it<8;it++){
      int id=it*256+tid;
      int kb=id&15, m=id>>4;
      uint4 v=*(const uint4*)(A+(size_t)(m0+m)*Kt+kc*128+kb*8);
      int byte=(m*256+kb*16)^((m&7)<<4);
      *(uint4*)((char*)lA+byte)=v;
    }
    #pragma unroll
    for(int it=0;it<4;it++){
      int id=it*256+tid;
      int kb=id&15, n=id>>4;
      uint4 v=*(const uint4*)(W+(size_t)(n0+n)*Kt+kc*128+kb*8);
      int byte=(n*256+kb*16)^((n&7)<<4);
      *(uint4*)((char*)lB+byte)=v;
    }
    __syncthreads();
    #pragma unroll
    for(int ks=0;ks<4;ks++){
      int kb=ks*4+(lane>>4);
      bfx8 bfr[2];
      #pragma unroll
      for(int nr=0;nr<2;nr++){
        int n=wn+nr*16+(lane&15);
        int byte=(n*256+kb*16)^((n&7)<<4);
        bfr[nr]=*(bfx8*)((char*)lB+byte);
      }
      #pragma unroll
      for(int mr=0;mr<4;mr++){
        int m=wm+mr*16+(lane&15);
        int byte=(m*256+kb*16)^((m&7)<<4);
        bfx8 afr=*(bfx8*)((char*)lA+byte);
        acc[mr][0]=__builtin_amdgcn_mfma_f32_16x16x32_bf16(afr,bfr[0],acc[mr][0],0,0,0);
        acc[mr][1]=__builtin_amdgcn_mfma_f32_16x16x32_bf16(afr,bfr[1],acc[mr][1],0,0,0);
      }
    }
  }
  int g=lane>>4, li=lane&15;
  #pragma unroll
  for(int mr=0;mr<4;mr++){
    #pragma unroll
    for(int r=0;r<4;r++){
      int row=m0+wm+mr*16+g*4+r;
      float inv=1.0f;
      if constexpr(EPI==3||EPI==4){
        if(EPI==3||(n0+wn)<128){
          // wave quadrant = 32 cols = one head; nr0^2+nr1^2 then 16-lane reduce
          float s=acc[mr][0][r]*acc[mr][0][r]+acc[mr][1][r]*acc[mr][1][r];
          s+=__shfl_xor(s,1); s+=__shfl_xor(s,2);
          s+=__shfl_xor(s,4); s+=__shfl_xor(s,8);
          inv=1.0f/fmaxf(sqrtf(s),1e-12f);
        }
      }
      #pragma unroll
      for(int nr=0;nr<2;nr++){
        int col=n0+wn+nr*16+li;
        float v=acc[mr][nr][r];
        if constexpr(EPI==0){
          if(col<Nreal) out[(size_t)row*682+col]=v+bias[col];
        } else if constexpr(EPI==1){
          out[(size_t)row*128+col]=v+bias[col]+resid[(size_t)row*128+col];
        } else if constexpr(EPI==2){
          out[(size_t)row*128+col]=geluf(v+bias[col]);
        } else if constexpr(EPI==3){
          float qn_=v*inv;
          int head=col>>5;
          float qs_=(qn_+qemb[col])*softplusf(temp[head])*seqs[0];
          out[(size_t)row*128+col]=qs_;
          out2[(size_t)row*128+col]=qn_;
        } else {
          float vv=((n0+wn)<128)? v*inv : v;
          out[(size_t)row*256+col]=vv;
        }
      }
    }
  }
}

// ============ 8x8 avg pool (xg 32768x128 -> xipre 512x128) ============
__global__ __launch_bounds__(128) void pool_kernel(const float* __restrict__ xg,
    float* __restrict__ xp){
  int bp=blockIdx.x; int b=bp>>6, pp=bp&63; int py=pp>>3, px=pp&7;
  int o=threadIdx.x;
  float s=0;
  for(int iy=0;iy<8;iy++)
    #pragma unroll
    for(int ix=0;ix<8;ix++)
      s+=xg[((size_t)b*NTOK+(py*8+iy)*64+px*8+ix)*128+o];
  xp[(size_t)bp*128+o]=s*(1.0f/64.0f);
}

// ============ pooled kv proj (verified, fp32) ============
__global__ __launch_bounds__(256) void kvp_kernel(const float* __restrict__ xi,
  const float* __restrict__ kvw, float* __restrict__ kpb, float* __restrict__ vpb){
  int bp=blockIdx.x;
  int b=bp>>6, p=bp&63;
  int o=threadIdx.x;
  __shared__ float xr[128];
  if(o<128) xr[o]=xi[(size_t)bp*128+o];
  __syncthreads();
  const float* wr=kvw+(size_t)o*128;
  float acc=0;
  for(int c=0;c<128;c++) acc+=xr[c]*wr[c];
  int hh=(o>>5)&3, d=o&31;
  if(o<128){
    float ss=acc*acc;
    #pragma unroll
    for(int m=1;m<32;m<<=1) ss+=__shfl_xor(ss,m);
    acc/=fmaxf(sqrtf(ss),1e-12f);
    kpb[(((size_t)b*4+hh)*64+p)*32+d]=acc;
  } else {
    vpb[(((size_t)b*4+hh)*64+p)*32+d]=acc;
  }
}

// ============ CPB MLP (verified) ============
__global__ __launch_bounds__(256) void cpb_kernel(const float* __restrict__ tbl,
  const float* __restrict__ w1, const float* __restrict__ b1,
  const float* __restrict__ w2, const float* __restrict__ b2, float* __restrict__ tout){
  int i=blockIdx.x;
  float c0=tbl[i*2], c1=tbl[i*2+1];
  int tid=threadIdx.x;
  float p0=0,p1=0,p2=0,p3=0;
  for(int j=tid;j<512;j+=256){
    float r=fmaxf(c0*w1[j*2]+c1*w1[j*2+1]+b1[j],0.0f);
    p0+=r*w2[j]; p1+=r*w2[512+j]; p2+=r*w2[1024+j]; p3+=r*w2[1536+j];
  }
  #pragma unroll
  for(int m=1;m<64;m<<=1){
    p0+=__shfl_xor(p0,m); p1+=__shfl_xor(p1,m);
    p2+=__shfl_xor(p2,m); p3+=__shfl_xor(p3,m);
  }
  __shared__ float red[4][4];
  int w=tid>>6;
  if((tid&63)==0){ red[w][0]=p0; red[w][1]=p1; red[w][2]=p2; red[w][3]=p3; }
  __syncthreads();
  if(tid<4)
    tout[(size_t)i*4+tid]=red[0][tid]+red[1][tid]+red[2][tid]+red[3][tid]+b2[tid];
}

// ============ attention v3b (verified round-8, unchanged) ============
__global__ __launch_bounds__(256) void attn3b_kernel(
  const float* __restrict__ qs, const float* __restrict__ qn,
  const float* __restrict__ kv_tm, const float* __restrict__ kp,
  const float* __restrict__ vp, const float* __restrict__ tb,
  const int* __restrict__ rpi, const float* __restrict__ relb,
  const float* __restrict__ ltok, const float* __restrict__ lbias,
  ushort* __restrict__ mid){
  int n0=blockIdx.x*4, h=blockIdx.y, b=blockIdx.z;
  int tt=threadIdx.x>>6, lane=threadIdx.x&63;
  int n=n0+tt;
  int y=n>>6, x=n&63;
  __shared__ float kp_s[64][33];
  __shared__ float vp_s[64][33];
  __shared__ float qs_s[4][32], qn_s[4][32];
  __shared__ float ap_sh[4][64];
  __shared__ float lm_sh[4][9];
  {
    size_t kb=((size_t)(b*4+h))*2048;
    for(int i=threadIdx.x;i<2048;i+=256){
      kp_s[i>>5][i&31]=kp[kb+i];
      vp_s[i>>5][i&31]=vp[kb+i];
    }
  }
  if(lane<32) qs_s[tt][lane]=qs[((size_t)b*NTOK+n)*128+h*32+lane];
  else        qn_s[tt][lane-32]=qn[((size_t)b*NTOK+n)*128+h*32+(lane-32)];
  __syncthreads();
  float lp;
  {
    float s=0;
    #pragma unroll
    for(int d=0;d<32;d++) s+=qs_s[tt][d]*kp_s[lane][d];
    lp=s+tb[(size_t)rpi[(size_t)n*64+lane]*4+h];
  }
  bool lval=lane<9;
  float ll=0.0f;
  if(lval){
    int dy=lane/3-1, dx=lane%3-1;
    int yy=y+dy, xx=x+dx;
    float s=0;
    if(yy>=0&&yy<64&&xx>=0&&xx<64){
      const float* kr=kv_tm+((size_t)b*NTOK+(size_t)(yy*64+xx))*256+h*32;
      #pragma unroll
      for(int d=0;d<32;d++) s+=qs_s[tt][d]*kr[d];
    }
    ll=s+relb[h*9+lane];
  }
  float m=lp; if(lval) m=fmaxf(m,ll);
  #pragma unroll
  for(int o=1;o<64;o<<=1) m=fmaxf(m,__shfl_xor(m,o));
  float ep=expf(lp-m);
  float el=lval?expf(ll-m):0.0f;
  float ssum=ep+el;
  #pragma unroll
  for(int o=1;o<64;o<<=1) ssum+=__shfl_xor(ssum,o);
  float inv=1.0f/ssum;
  ap_sh[tt][lane]=ep*inv;
  if(lval){
    float lm=lbias[h*9+lane]+el*inv;
    #pragma unroll
    for(int d=0;d<32;d++) lm+=qn_s[tt][d]*ltok[(size_t)(h*32+d)*9+lane];
    lm_sh[tt][lane]=lm;
  }
  __syncthreads();
  if(lane<32){
    int d=lane;
    float acc=0;
    #pragma unroll
    for(int l=0;l<9;l++){
      int dy=l/3-1, dx=l%3-1;
      int yy=y+dy, xx=x+dx;
      if(yy>=0&&yy<64&&xx>=0&&xx<64)
        acc+=lm_sh[tt][l]*kv_tm[((size_t)b*NTOK+(size_t)(yy*64+xx))*256+128+h*32+d];
    }
    #pragma unroll
    for(int p=0;p<64;p++) acc+=ap_sh[tt][p]*vp_s[p][d];
    mid[((size_t)b*NTOK+n)*128+h*32+d]=f2bf(acc);
  }
}

// ============ depthwise 3x3 + gelu*gate -> act_bf (verified) ============
__global__ __launch_bounds__(256) void dwconv_kernel(const float* __restrict__ u,
    const float* __restrict__ dww, const float* __restrict__ dwb, ushort* __restrict__ act){
  int c0=blockIdx.x*32;
  int cwReal=341-c0; if(cwReal>32) cwReal=32;
  int y0=blockIdx.y*2;
  int b=blockIdx.z;
  int tid=threadIdx.x;
  __shared__ float gsh[4][64][33];
  for(int it=0;it<32;it++){
    int idx=it*256+tid;
    int cc=idx&31;
    int px=(idx>>5)&63;
    int row=idx>>11;
    int yy=y0-1+row;
    float v=0.0f;
    if(yy>=0&&yy<64&&cc<cwReal)
      v=u[((size_t)b*NTOK+yy*64+px)*682+c0+cc];
    gsh[row][px][cc]=v;
  }
  __syncthreads();
  int cc=tid&31, pxb=tid>>5;
  int c=c0+cc;
  if(c>=384) return;
  if(cc<cwReal){
    float w0=dww[c*9+0],w1=dww[c*9+1],w2=dww[c*9+2],
          w3=dww[c*9+3],w4=dww[c*9+4],w5=dww[c*9+5],
          w6=dww[c*9+6],w7=dww[c*9+7],w8=dww[c*9+8];
    float bias=dwb[c];
    for(int ty=0;ty<2;ty++){
      for(int pxi=0;pxi<8;pxi++){
        int px=pxi*8+pxb;
        float ss=0.0f;
        if(px>0){ ss+=gsh[ty][px-1][cc]*w0+gsh[ty+1][px-1][cc]*w3+gsh[ty+2][px-1][cc]*w6; }
        ss+=gsh[ty][px][cc]*w1+gsh[ty+1][px][cc]*w4+gsh[ty+2][px][cc]*w7;
        if(px<63){ ss+=gsh[ty][px+1][cc]*w2+gsh[ty+1][px+1][cc]*w5+gsh[ty+2][px+1][cc]*w8; }
        float z=ss+bias;
        int nn=(y0+ty)*64+px;
        float gate=u[((size_t)b*NTOK+nn)*682+341+c];
        act[((size_t)b*NTOK+nn)*384+c]=f2bf(geluf(z)*gate);
      }
    }
  } else {
    for(int ty=0;ty<2;ty++)
      for(int pxi=0;pxi<8;pxi++){
        int px=pxi*8+pxb;
        int nn=(y0+ty)*64+px;
        act[((size_t)b*NTOK+nn)*384+c]=0;
      }
  }
}

extern "C" void kernel_launch(void* const* d_in, const int* in_sizes, int n_in,
                              void* d_out, int out_size, void* d_ws, size_t ws_size,
                              hipStream_t stream){
  const float* x     =(const float*)d_in[0];
  const float* n1g   =(const float*)d_in[1];
  const float* n1b   =(const float*)d_in[2];
  const float* qw    =(const float*)d_in[3];
  const float* kvw   =(const float*)d_in[4];
  const float* temp  =(const float*)d_in[5];
  const float* qemb  =(const float*)d_in[6];
  const float* relb  =(const float*)d_in[7];
  const float* ltok  =(const float*)d_in[8];
  const float* lbias =(const float*)d_in[9];
  const float* srw   =(const float*)d_in[10];
  const float* srb   =(const float*)d_in[11];
  const float* npg   =(const float*)d_in[12];
  const float* npb   =(const float*)d_in[13];
  const float* cpb1w =(const float*)d_in[14];
  const float* cpb1b =(const float*)d_in[15];
  const float* cpb2w =(const float*)d_in[16];
  const float* cpb2b =(const float*)d_in[17];
  const float* projw =(const float*)d_in[18];
  const float* projb =(const float*)d_in[19];
  const float* n2g   =(const float*)d_in[20];
  const float* n2b   =(const float*)d_in[21];
  const float* fc1w  =(const float*)d_in[22];
  const float* fc1b  =(const float*)d_in[23];
  const float* dww   =(const float*)d_in[24];
  const float* dwb   =(const float*)d_in[25];
  const float* fc2w  =(const float*)d_in[26];
  const float* fc2b  =(const float*)d_in[27];
  const float* ctab  =(const float*)d_in[28];
  const float* seqs  =(const float*)d_in[29];
  const int*   rpi   =(const int*)d_in[30];

  char* base=(char*)d_ws;
  ushort* h_bf  =(ushort*)(base+0);           // 8.4 MB (dead after 3 GEMMs); reused as h2_bf
  float*  qs_b  =(float*)(base+8388608);      // 16.8 MB (dead after attn)
  float*  qn_b  =(float*)(base+25165824);     // 16.8 MB (dead after attn)
  float*  kv_tm =(float*)(base+41943040);     // 33.5 MB token-major (dead after attn)
  float*  xg    =(float*)(base+75497472);     // 16.8 MB (dead after pool)
  ushort* mid_bf=(ushort*)(base+92274688);    // 8.4 MB (dead after proj)
  float*  x2    =(float*)(base+100663296);    // 16.8 MB (live until fc2)
  float*  u_buf =(float*)(base+8388608);      // 89.4 MB overlay of qs..mid (all dead by fc1)
  ushort* act_bf=(ushort*)(base+117440512);   // 25.2 MB
  float*  xipre =(float*)(base+142606336);
  float*  xi    =(float*)(base+142868480);
  float*  kp    =(float*)(base+143130624);
  float*  vp    =(float*)(base+143392768);
  float*  tbuf  =(float*)(base+143654912);
  ushort* qwb   =(ushort*)(base+143671296);
  ushort* kvwb  =(ushort*)(base+143704064);
  ushort* srwb  =(ushort*)(base+143769600);
  ushort* pwb   =(ushort*)(base+143802368);
  ushort* f1wb  =(ushort*)(base+143835136);
  ushort* f2wb  =(ushort*)(base+144015360);   // ends 144113664
  ushort* h2_bf =h_bf;

  convw_kernel<<<864,256,0,stream>>>(qw,kvw,srw,projw,fc1w,fc2w,qwb,kvwb,srwb,pwb,f1wb,f2wb);
  ln_bf_kernel<<<32768,128,0,stream>>>(x,n1g,n1b,h_bf);
  gemm_kernel<1,3><<<dim3(256,2),256,0,stream>>>(h_bf,qwb,nullptr,nullptr,qs_b,qn_b,128,qemb,temp,seqs);
  gemm_kernel<1,4><<<dim3(256,4),256,0,stream>>>(h_bf,kvwb,nullptr,nullptr,kv_tm,nullptr,256,nullptr,nullptr,nullptr);
  gemm_kernel<1,2><<<dim3(256,2),256,0,stream>>>(h_bf,srwb,srb,nullptr,xg,nullptr,128,nullptr,nullptr,nullptr);
  pool_kernel<<<512,128,0,stream>>>(xg,xipre);
  ln_f32_kernel<<<512,128,0,stream>>>(xipre,npg,npb,xi);
  kvp_kernel<<<512,256,0,stream>>>(xi,kvw,kp,vp);
  cpb_kernel<<<1024,256,0,stream>>>(ctab,cpb1w,cpb1b,cpb2w,cpb2b,tbuf);
  attn3b_kernel<<<dim3(1024,4,8),256,0,stream>>>(qs_b,qn_b,kv_tm,kp,vp,tbuf,rpi,relb,ltok,lbias,mid_bf);
  gemm_kernel<1,1><<<dim3(256,2),256,0,stream>>>(mid_bf,pwb,projb,x,x2,nullptr,128,nullptr,nullptr,nullptr);
  ln_bf_kernel<<<32768,128,0,stream>>>(x2,n2g,n2b,h2_bf);
  gemm_kernel<1,0><<<dim3(256,11),256,0,stream>>>(h2_bf,f1wb,fc1b,nullptr,u_buf,nullptr,682,nullptr,nullptr,nullptr);
  dwconv_kernel<<<dim3(12,32,8),256,0,stream>>>(u_buf,dww,dwb,act_bf);
  gemm_kernel<3,1><<<dim3(256,2),256,0,stream>>>(act_bf,f2wb,fc2b,x2,(float*)d_out,nullptr,128,nullptr,nullptr,nullptr);
}